// Round 15
// baseline (29.560 us; speedup 1.0000x reference)
//
#include <hip/hip_runtime.h>
#include <hip/hip_bf16.h>
#include <hip/hip_fp16.h>
#include <math.h>

// Problem constants (from reference setup_inputs)
#define B_ROWS 256
#define D_IN   128
#define D_OUT  256
#define M_LEN  4096
#define BETA   50.0f

// out layout (f32): loss[256] | mem_out[4096*256] | md_out[4096*128]
#define OFF_MEM  (B_ROWS)
#define OFF_MD   (B_ROWS + M_LEN * D_OUT)

#define H2(f) __builtin_bit_cast(__half2, f)

// ---------------------------------------------------------------------------
// K1 (k_prep): enc = tanh(norm(x)@W1+b1) and loss init to +inf.
// 256 blocks x 256 threads (one block per batch row).  [r5-proven]
// ---------------------------------------------------------------------------
__global__ __launch_bounds__(256) void k_prep(
    const float* __restrict__ x, const float* __restrict__ mean,
    const float* __restrict__ stdv, const float* __restrict__ W1,
    const float* __restrict__ b1, float* __restrict__ enc,
    float* __restrict__ out) {
  __shared__ float sx[D_IN];
  const int b = blockIdx.x, j = threadIdx.x;
  if (j < D_IN) {
    float s = stdv[j];
    sx[j] = (s == 0.0f) ? 0.0f : (x[b * D_IN + j] - mean[j]) / s;
  }
  __syncthreads();
  float acc = b1[j];
#pragma unroll 8
  for (int k = 0; k < D_IN; ++k) acc = fmaf(sx[k], W1[k * D_OUT + j], acc);
  enc[b * D_OUT + j] = tanhf(acc);
  if (b == 0) ((unsigned int*)out)[j] = 0x7F800000u;  // +inf loss init
}

// ---------------------------------------------------------------------------
// K2 (k_dist): loss[b] = min_m sum_d |enc[b,d] - memory[m,d]|
// [r13 champion structure; change: PACKED F16 inner loop. Tiles stage as
//  half2 (cvt_pkrtz on staging); per packed k-pair: hsub2+habs2+hadd2 =
//  1.5 VALU/pair (-25%) and 3 b128 per 2 k-layers (-50% LDS reads).
//  Accumulate in f16 (per-half sums <= ~32, error ~0.3 << 5.16 threshold);
//  unpack to f32 before the combine tree. LDS 48->32 KB.]
// 512 blocks (64 m-tiles x 8 b-tiles) x 256 threads. Tile 32b x 64m.
// k-split 4: wave w owns k in [64w,64w+64), 2 chunks of 32 k, PRIVATE LDS
// region -> NO barriers in the main loop. 4x8 microtile/lane.
// Swizzles (re-derived for half2): E row^4lk, M col^8(lk&3) -> staging
// stores <=2-way, compute reads broadcast/2-way (all free).
// 4-deep rotating register prefetch (compile-time indices).
// Fused FULL memory->out / mem_data->out copy (loads early, stores late).
// ---------------------------------------------------------------------------
#define TB 32
#define TM 64

__global__ __launch_bounds__(256) void k_dist(
    const float* __restrict__ enc, const float* __restrict__ mem,
    const float4* __restrict__ mem4, const float4* __restrict__ md4,
    float* __restrict__ out) {
  __shared__ __align__(16) float sf[8192];  // 32KB; wave w owns [w*2048,+2048)
  __half2* sh = reinterpret_cast<__half2*>(sf);

  const int t  = threadIdx.x;
  const int w  = t >> 6;     // wave id -> k-quarter
  const int l  = t & 63;
  const int ro = l >> 3;     // 0..7 staging row-offset; compute tr
  const int q  = l & 7;      // 0..7 staging f4-k index; compute tc
  const int m0 = blockIdx.x * TM;
  const int b0 = blockIdx.y * TB;
  const int bid = blockIdx.y * 64 + blockIdx.x;  // gridDim.x == 64

  const float* encp = enc + (b0 + ro) * D_OUT + w * 64 + q * 4;
  const float* memp = mem + (m0 + ro) * D_OUT + w * 64 + q * 4;

  // per-wave half2 regions: E [w*2048, +512) : [kk2<16][32 rows], 
  //                         M [w*2048+512, +1024) : [kk2<16][64 cols]
  const int web = w * 2048;
  const int wmb = w * 2048 + 512;
  const int lk  = q;                 // staging f4-k index alias

  float4 rE[4], rM[8], rE2[4], rM2[8];
  __half2 acc_h[4][8];
#pragma unroll
  for (int i = 0; i < 4; ++i)
#pragma unroll
    for (int j = 0; j < 8; ++j) acc_h[i][j] = __float2half2_rn(0.0f);

  auto store_lds = [&](const float4* e, const float4* m) {
    const int eb0 = web + (2 * lk) * 32;
    const int mb0 = wmb + (2 * lk) * 64;
#pragma unroll
    for (int i = 0; i < 4; ++i) {
      __half2 h0 = __float22half2_rn(make_float2(e[i].x, e[i].y));
      __half2 h1 = __float22half2_rn(make_float2(e[i].z, e[i].w));
      const int rp = (ro + 8 * i) ^ (4 * lk);   // swzE
      sh[eb0 + rp] = h0;
      sh[eb0 + 32 + rp] = h1;
    }
#pragma unroll
    for (int i = 0; i < 8; ++i) {
      __half2 g0 = __float22half2_rn(make_float2(m[i].x, m[i].y));
      __half2 g1 = __float22half2_rn(make_float2(m[i].z, m[i].w));
      const int cp = (ro + 8 * i) ^ (8 * (lk & 3));  // swzM
      sh[mb0 + cp] = g0;
      sh[mb0 + 64 + cp] = g1;
    }
  };

  auto rdE = [&](int kk2) -> float4 {   // 4 rows (half2 each) at packed-k kk2
    const int u = (kk2 >> 1) & 7;
    return *(const float4*)&sh[web + kk2 * 32 + ((4 * ro) ^ (4 * u))];
  };
  auto rdM1 = [&](int kk2) -> float4 {  // cols 8q..8q+3
    const int u = (kk2 >> 1) & 3;
    return *(const float4*)&sh[wmb + kk2 * 64 + ((8 * q) ^ (8 * u))];
  };
  auto rdM2 = [&](int kk2) -> float4 {  // cols 8q+4..8q+7
    const int u = (kk2 >> 1) & 3;
    return *(const float4*)&sh[wmb + kk2 * 64 + ((8 * q) ^ (8 * u)) + 4];
  };

  auto compute = [&]() {
    __builtin_amdgcn_s_setprio(1);
    float4 bE[4], bM1[4], bM2[4];  // rotating prefetch regs (static indices)
#pragma unroll
    for (int p = 0; p < 4; ++p) {
      bE[p] = rdE(p); bM1[p] = rdM1(p); bM2[p] = rdM2(p);
    }
#pragma unroll
    for (int kk2 = 0; kk2 < 16; ++kk2) {
      const int s = kk2 & 3;
      float4 a  = bE[s];
      float4 v1 = bM1[s];
      float4 v2 = bM2[s];
      if (kk2 + 4 < 16) {  // issue kk2+4's reads before this layer's VALU
        bE[s] = rdE(kk2 + 4); bM1[s] = rdM1(kk2 + 4); bM2[s] = rdM2(kk2 + 4);
      }
      __half2 av[4]  = {H2(a.x), H2(a.y), H2(a.z), H2(a.w)};
      __half2 b1h[4] = {H2(v1.x), H2(v1.y), H2(v1.z), H2(v1.w)};
      __half2 b2h[4] = {H2(v2.x), H2(v2.y), H2(v2.z), H2(v2.w)};
#pragma unroll
      for (int i = 0; i < 4; ++i)
#pragma unroll
        for (int j = 0; j < 4; ++j) {
          acc_h[i][j]     = __hadd2(acc_h[i][j],
                                    __habs2(__hsub2(av[i], b1h[j])));
          acc_h[i][j + 4] = __hadd2(acc_h[i][j + 4],
                                    __habs2(__hsub2(av[i], b2h[j])));
        }
    }
    __builtin_amdgcn_s_setprio(0);
  };

  // chunk 0 loads (coalesced: 8 consecutive lanes = 128B run)
#pragma unroll
  for (int i = 0; i < 4; ++i) rE[i] = *(const float4*)(encp + i * 8 * D_OUT);
#pragma unroll
  for (int i = 0; i < 8; ++i) rM[i] = *(const float4*)(memp + i * 8 * D_OUT);
  store_lds(rE, rM);

  // prefetch chunk 1 (+32 k)
#pragma unroll
  for (int i = 0; i < 4; ++i) rE2[i] = *(const float4*)(encp + 32 + i * 8 * D_OUT);
#pragma unroll
  for (int i = 0; i < 8; ++i) rM2[i] = *(const float4*)(memp + 32 + i * 8 * D_OUT);

  // fused output-copy loads (complete by the tail stores)
  float4 cm0 = mem4[bid * 512 + t];
  float4 cm1 = mem4[bid * 512 + 256 + t];
  float4 cd0 = md4[bid * 256 + t];

  compute();               // chunk 0
  store_lds(rE2, rM2);     // same-wave WAR on LDS: in-order per wave
  compute();               // chunk 1

  // ---- combine across the 4 k-quarter waves (f32, own-region dump) ----
#pragma unroll
  for (int i = 0; i < 4; ++i)
#pragma unroll
    for (int j = 0; j < 8; ++j) {
      float2 pr = __half22float2(acc_h[i][j]);
      const int p = i * 8 + j;
      sf[w * 2048 + l * 32 + (p ^ (l & 31))] = pr.x + pr.y;
    }
  __syncthreads();

  // summer: thread t handles b-row r = t>>3, m-cols (t&7)*8..+7
  {
    const int r = t >> 3, cg = t & 7;
    const int lv = (r >> 2) * 8 + cg;
    float dmin = 3.4e38f;
#pragma unroll
    for (int j = 0; j < 8; ++j) {
      const int p = (r & 3) * 8 + j;
      float s = sf[0 * 2048 + lv * 32 + (p ^ (lv & 31))];
      s += sf[1 * 2048 + lv * 32 + (p ^ (lv & 31))];
      s += sf[2 * 2048 + lv * 32 + (p ^ (lv & 31))];
      s += sf[3 * 2048 + lv * 32 + (p ^ (lv & 31))];
      dmin = fminf(dmin, s);
    }
    dmin = fminf(dmin, __shfl_xor(dmin, 1));
    dmin = fminf(dmin, __shfl_xor(dmin, 2));
    dmin = fminf(dmin, __shfl_xor(dmin, 4));
    if (cg == 0)  // distances >= 0, init +inf -> uint-bit atomicMin valid
      atomicMin((unsigned int*)out + (b0 + r), __float_as_uint(dmin));
  }

  // ---- complete fused copy ----
  float4* mo = (float4*)(out + OFF_MEM);
  float4* dd = (float4*)(out + OFF_MD);
  mo[bid * 512 + t] = cm0;
  mo[bid * 512 + 256 + t] = cm1;
  dd[bid * 256 + t] = cd0;
}

// ---------------------------------------------------------------------------
// K3 (k_scatter): sequential circular-buffer update collapsed to
// ballot/prefix + scatter (count starts at M_LEN so positions wrap from 0).
// ---------------------------------------------------------------------------
__global__ __launch_bounds__(256) void k_scatter(float* __restrict__ out,
                                                 const float* __restrict__ enc,
                                                 const float* __restrict__ x) {
  __shared__ int wcount[4];
  int t = threadIdx.x;
  float l = out[t];  // final loss
  bool cond = isfinite(l) && (l <= BETA);
  unsigned long long m = __ballot(cond);
  int lane = t & 63;
  int wv   = t >> 6;
  int pre_in_wave = __popcll(m & ((1ull << lane) - 1ull));
  if (lane == 0) wcount[wv] = (int)__popcll(m);
  __syncthreads();
  int base = 0;
  for (int w = 0; w < wv; ++w) base += wcount[w];
  if (cond) {
    int pos = base + pre_in_wave;  // (M_LEN + prefix) % M_LEN
    float* mrow = out + OFF_MEM + pos * D_OUT;
    const float* erow = enc + t * D_OUT;
    for (int d = 0; d < D_OUT; ++d) mrow[d] = erow[d];
    float* drow = out + OFF_MD + pos * D_IN;
    const float* xrow = x + t * D_IN;
    for (int d = 0; d < D_IN; ++d) drow[d] = xrow[d];
  }
}

// ---------------------------------------------------------------------------
extern "C" void kernel_launch(void* const* d_in, const int* in_sizes, int n_in,
                              void* d_out, int out_size, void* d_ws, size_t ws_size,
                              hipStream_t stream) {
  const float* x      = (const float*)d_in[0];
  const float* mean   = (const float*)d_in[1];
  const float* stdv   = (const float*)d_in[2];
  const float* W1     = (const float*)d_in[3];
  const float* b1     = (const float*)d_in[4];
  const float* memory = (const float*)d_in[5];
  const float* memdat = (const float*)d_in[6];
  float* out = (float*)d_out;
  float* enc = (float*)d_ws;  // 256*256*4 = 256KB scratch

  k_prep<<<dim3(B_ROWS), dim3(256), 0, stream>>>(x, mean, stdv, W1, b1, enc, out);

  k_dist<<<dim3(M_LEN / TM, B_ROWS / TB), dim3(256), 0, stream>>>(
      enc, memory, (const float4*)memory, (const float4*)memdat, out);

  k_scatter<<<dim3(1), dim3(256), 0, stream>>>(out, enc, x);
}

// Round 16
// 26.736 us; speedup vs baseline: 1.1056x; 1.1056x over previous
//
#include <hip/hip_runtime.h>
#include <hip/hip_bf16.h>
#include <math.h>

// Problem constants (from reference setup_inputs)
#define B_ROWS 256
#define D_IN   128
#define D_OUT  256
#define M_LEN  4096
#define BETA   50.0f

// out layout (f32): loss[256] | mem_out[4096*256] | md_out[4096*128]
#define OFF_MEM  (B_ROWS)
#define OFF_MD   (B_ROWS + M_LEN * D_OUT)

// ---------------------------------------------------------------------------
// K1 (k_prep): enc = tanh(norm(x)@W1+b1) and loss init to +inf.
// 256 blocks x 256 threads (one block per batch row).  [r5-proven]
// ---------------------------------------------------------------------------
__global__ __launch_bounds__(256) void k_prep(
    const float* __restrict__ x, const float* __restrict__ mean,
    const float* __restrict__ stdv, const float* __restrict__ W1,
    const float* __restrict__ b1, float* __restrict__ enc,
    float* __restrict__ out) {
  __shared__ float sx[D_IN];
  const int b = blockIdx.x, j = threadIdx.x;
  if (j < D_IN) {
    float s = stdv[j];
    sx[j] = (s == 0.0f) ? 0.0f : (x[b * D_IN + j] - mean[j]) / s;
  }
  __syncthreads();
  float acc = b1[j];
#pragma unroll 8
  for (int k = 0; k < D_IN; ++k) acc = fmaf(sx[k], W1[k * D_OUT + j], acc);
  enc[b * D_OUT + j] = tanhf(acc);
  if (b == 0) ((unsigned int*)out)[j] = 0x7F800000u;  // +inf loss init
}

// ---------------------------------------------------------------------------
// K2 (k_dist): loss[b] = min_m sum_d |enc[b,d] - memory[m,d]|
// [r14 champion: measured optimum across 10 structural variants.
//  512 blocks (64 m-tiles x 8 b-tiles) x 256 threads; tile 32b x 64m;
//  k-split 4 (wave w owns k in [64w,64w+64), 2 chunks of 32 kk) with
//  PRIVATE per-wave LDS regions -> no barriers in the main loop; 4x8
//  microtile/lane; 4-deep rotating register prefetch; XOR swizzle
//  row^=4*(k>>2) -> all LDS traffic <=2-way; f32 arithmetic (f16 packed
//  measured worse, r15); VOP3 |abs| fold verified (r14); setprio kept
//  (neutral, harmless); fused FULL output copy (loads early, stores late).]
// ---------------------------------------------------------------------------
#define TB 32
#define TM 64

__global__ __launch_bounds__(256) void k_dist(
    const float* __restrict__ enc, const float* __restrict__ mem,
    const float4* __restrict__ mem4, const float4* __restrict__ md4,
    float* __restrict__ out) {
  __shared__ __align__(16) float sE[4][32][TB];  // [wave][kk][row^swz] 16KB
  __shared__ __align__(16) float sM[4][32][TM];  // [wave][kk][row^swz] 32KB

  const int t  = threadIdx.x;
  const int w  = t >> 6;     // wave id -> k-quarter
  const int l  = t & 63;
  const int ro = l >> 3;     // 0..7 staging row-offset; compute tr
  const int q  = l & 7;      // 0..7 staging f4-k index; compute tc
  const int m0 = blockIdx.x * TM;
  const int b0 = blockIdx.y * TB;
  const int bid = blockIdx.y * 64 + blockIdx.x;  // gridDim.x == 64

  const float* encp = enc + (b0 + ro) * D_OUT + w * 64 + q * 4;
  const float* memp = mem + (m0 + ro) * D_OUT + w * 64 + q * 4;

  float4 rE[4], rM[8], rE2[4], rM2[8];
  float acc[4][8] = {};

  auto store_lds = [&](const float4* e, const float4* m) {
#pragma unroll
    for (int i = 0; i < 4; ++i) {
      const int row = (i * 8 + ro) ^ (q * 4);
      sE[w][q * 4 + 0][row] = e[i].x;
      sE[w][q * 4 + 1][row] = e[i].y;
      sE[w][q * 4 + 2][row] = e[i].z;
      sE[w][q * 4 + 3][row] = e[i].w;
    }
#pragma unroll
    for (int i = 0; i < 8; ++i) {
      const int row = (i * 8 + ro) ^ (q * 4);
      sM[w][q * 4 + 0][row] = m[i].x;
      sM[w][q * 4 + 1][row] = m[i].y;
      sM[w][q * 4 + 2][row] = m[i].z;
      sM[w][q * 4 + 3][row] = m[i].w;
    }
  };

  auto rdE = [&](int kk) -> float4 {
    const int sw = (kk >> 2) * 4;
    return *(const float4*)&sE[w][kk][(ro * 4) ^ sw];
  };
  auto rdM1 = [&](int kk) -> float4 {
    const int sw = (kk >> 2) * 4;
    return *(const float4*)&sM[w][kk][(q * 8) ^ sw];
  };
  auto rdM2 = [&](int kk) -> float4 {
    const int sw = (kk >> 2) * 4;
    return *(const float4*)&sM[w][kk][(q * 8 + 4) ^ sw];
  };

  auto compute = [&]() {
    __builtin_amdgcn_s_setprio(1);   // favor VALU-phase waves
    float4 bE[4], bM1[4], bM2[4];  // rotating prefetch regs (static indices)
#pragma unroll
    for (int p = 0; p < 4; ++p) {
      bE[p] = rdE(p); bM1[p] = rdM1(p); bM2[p] = rdM2(p);
    }
#pragma unroll
    for (int kk = 0; kk < 32; ++kk) {
      const int s = kk & 3;
      float4 a  = bE[s];
      float4 v1 = bM1[s];
      float4 v2 = bM2[s];
      if (kk + 4 < 32) {  // issue kk+4's reads before kk's 64 VALU ops
        bE[s] = rdE(kk + 4); bM1[s] = rdM1(kk + 4); bM2[s] = rdM2(kk + 4);
      }
      float av[4] = {a.x, a.y, a.z, a.w};
      float bw[8] = {v1.x, v1.y, v1.z, v1.w, v2.x, v2.y, v2.z, v2.w};
#pragma unroll
      for (int i = 0; i < 4; ++i)
#pragma unroll
        for (int j = 0; j < 8; ++j) {
          float d = av[i] - bw[j];
          // forced VOP3 abs-modifier add: exactly 2 VALU per pair
          asm("v_add_f32 %0, %0, |%1|" : "+v"(acc[i][j]) : "v"(d));
        }
    }
    __builtin_amdgcn_s_setprio(0);
  };

  // chunk 0 loads (coalesced: 8 consecutive lanes = 128B run)
#pragma unroll
  for (int i = 0; i < 4; ++i) rE[i] = *(const float4*)(encp + i * 8 * D_OUT);
#pragma unroll
  for (int i = 0; i < 8; ++i) rM[i] = *(const float4*)(memp + i * 8 * D_OUT);
  store_lds(rE, rM);

  // prefetch chunk 1 (+32 k)
#pragma unroll
  for (int i = 0; i < 4; ++i) rE2[i] = *(const float4*)(encp + 32 + i * 8 * D_OUT);
#pragma unroll
  for (int i = 0; i < 8; ++i) rM2[i] = *(const float4*)(memp + 32 + i * 8 * D_OUT);

  // fused output-copy loads (complete by the tail stores)
  float4 cm0 = mem4[bid * 512 + t];
  float4 cm1 = mem4[bid * 512 + 256 + t];
  float4 cd0 = md4[bid * 256 + t];

  compute();               // chunk 0
  store_lds(rE2, rM2);     // same-wave WAR on LDS: in-order per wave
  compute();               // chunk 1

  // ---- combine across the 4 k-quarter waves ----
  float* sf = &sM[0][0][0];
#pragma unroll
  for (int i = 0; i < 4; ++i)
#pragma unroll
    for (int j = 0; j < 8; ++j) {
      const int p = i * 8 + j;
      sf[w * 2048 + l * 32 + (p ^ (l & 31))] = acc[i][j];
    }
  __syncthreads();

  // summer: thread t handles b-row r = t>>3, m-cols (t&7)*8..+7
  {
    const int r = t >> 3, cg = t & 7;
    const int lv = (r >> 2) * 8 + cg;
    float dmin = 3.4e38f;
#pragma unroll
    for (int j = 0; j < 8; ++j) {
      const int p = (r & 3) * 8 + j;
      float s = sf[0 * 2048 + lv * 32 + (p ^ (lv & 31))];
      s += sf[1 * 2048 + lv * 32 + (p ^ (lv & 31))];
      s += sf[2 * 2048 + lv * 32 + (p ^ (lv & 31))];
      s += sf[3 * 2048 + lv * 32 + (p ^ (lv & 31))];
      dmin = fminf(dmin, s);
    }
    dmin = fminf(dmin, __shfl_xor(dmin, 1));
    dmin = fminf(dmin, __shfl_xor(dmin, 2));
    dmin = fminf(dmin, __shfl_xor(dmin, 4));
    if (cg == 0)  // distances >= 0, init +inf -> uint-bit atomicMin valid
      atomicMin((unsigned int*)out + (b0 + r), __float_as_uint(dmin));
  }

  // ---- complete fused copy ----
  float4* mo = (float4*)(out + OFF_MEM);
  float4* dd = (float4*)(out + OFF_MD);
  mo[bid * 512 + t] = cm0;
  mo[bid * 512 + 256 + t] = cm1;
  dd[bid * 256 + t] = cd0;
}

// ---------------------------------------------------------------------------
// K3 (k_scatter): sequential circular-buffer update collapsed to
// ballot/prefix + scatter (count starts at M_LEN so positions wrap from 0).
// ---------------------------------------------------------------------------
__global__ __launch_bounds__(256) void k_scatter(float* __restrict__ out,
                                                 const float* __restrict__ enc,
                                                 const float* __restrict__ x) {
  __shared__ int wcount[4];
  int t = threadIdx.x;
  float l = out[t];  // final loss
  bool cond = isfinite(l) && (l <= BETA);
  unsigned long long m = __ballot(cond);
  int lane = t & 63;
  int wv   = t >> 6;
  int pre_in_wave = __popcll(m & ((1ull << lane) - 1ull));
  if (lane == 0) wcount[wv] = (int)__popcll(m);
  __syncthreads();
  int base = 0;
  for (int w = 0; w < wv; ++w) base += wcount[w];
  if (cond) {
    int pos = base + pre_in_wave;  // (M_LEN + prefix) % M_LEN
    float* mrow = out + OFF_MEM + pos * D_OUT;
    const float* erow = enc + t * D_OUT;
    for (int d = 0; d < D_OUT; ++d) mrow[d] = erow[d];
    float* drow = out + OFF_MD + pos * D_IN;
    const float* xrow = x + t * D_IN;
    for (int d = 0; d < D_IN; ++d) drow[d] = xrow[d];
  }
}

// ---------------------------------------------------------------------------
extern "C" void kernel_launch(void* const* d_in, const int* in_sizes, int n_in,
                              void* d_out, int out_size, void* d_ws, size_t ws_size,
                              hipStream_t stream) {
  const float* x      = (const float*)d_in[0];
  const float* mean   = (const float*)d_in[1];
  const float* stdv   = (const float*)d_in[2];
  const float* W1     = (const float*)d_in[3];
  const float* b1     = (const float*)d_in[4];
  const float* memory = (const float*)d_in[5];
  const float* memdat = (const float*)d_in[6];
  float* out = (float*)d_out;
  float* enc = (float*)d_ws;  // 256*256*4 = 256KB scratch

  k_prep<<<dim3(B_ROWS), dim3(256), 0, stream>>>(x, mean, stdv, W1, b1, enc, out);

  k_dist<<<dim3(M_LEN / TM, B_ROWS / TB), dim3(256), 0, stream>>>(
      enc, memory, (const float4*)memory, (const float4*)memdat, out);

  k_scatter<<<dim3(1), dim3(256), 0, stream>>>(out, enc, x);
}